// Round 4
// baseline (1087.642 us; speedup 1.0000x reference)
//
#include <hip/hip_runtime.h>
#include <math.h>

#define Bn 128
#define Tn 512
#define Dn 32
#define Hn 128
#define Gn 512   // 4*H
#define Ln 3

// LDS-only barrier: does NOT drain vmcnt.
#define BAR_LDS() asm volatile("s_waitcnt lgkmcnt(0)\n\ts_barrier" ::: "memory")

typedef _Float16 h2 __attribute__((ext_vector_type(2)));
typedef _Float16 half8 __attribute__((ext_vector_type(8)));   // MFMA A/B frag
typedef float f32x4 __attribute__((ext_vector_type(4)));      // MFMA acc

__device__ __forceinline__ float dot2(h2 a, h2 b, float c) {
    return __builtin_amdgcn_fdot2(a, b, c, false);
}
__device__ __forceinline__ h2 pkh(float a, float b) {
    h2 r; r.x = (_Float16)a; r.y = (_Float16)b; return r;
}
__device__ __forceinline__ float sigm(float x) {
    return __builtin_amdgcn_rcpf(1.f + __expf(-x));
}
__device__ __forceinline__ float tanh_fast(float x) {
    return 1.f - 2.f * __builtin_amdgcn_rcpf(1.f + __expf(2.f * x));
}

// quad-local butterfly add via DPP (no DS pipe, ~4cyc dep latency).
// xor1 = quad_perm(1,0,3,2) = 0xB1 ; xor2 = quad_perm(2,3,0,1) = 0x4E
#define DPPADD(a, CTRL) { \
    int _t = __builtin_amdgcn_update_dpp(0, __builtin_bit_cast(int, a), \
                                         CTRL, 0xF, 0xF, true); \
    a += __builtin_bit_cast(float, _t); }

#define KEEPH(x) asm volatile("" : "+v"(x))
#define LD8H(p) (*(const half8*)(p))
#define H2OF(V, i) (((const h2*)&(V))[i])

#define DECL16(P, R) \
  h2 P##0=pkh(R[0],R[1]),   P##1=pkh(R[2],R[3]),   P##2=pkh(R[4],R[5]),   P##3=pkh(R[6],R[7]),   \
     P##4=pkh(R[8],R[9]),   P##5=pkh(R[10],R[11]), P##6=pkh(R[12],R[13]), P##7=pkh(R[14],R[15]), \
     P##8=pkh(R[16],R[17]), P##9=pkh(R[18],R[19]), P##10=pkh(R[20],R[21]),P##11=pkh(R[22],R[23]),\
     P##12=pkh(R[24],R[25]),P##13=pkh(R[26],R[27]),P##14=pkh(R[28],R[29]),P##15=pkh(R[30],R[31]);
#define KEEP16(P) \
  KEEPH(P##0); KEEPH(P##1); KEEPH(P##2); KEEPH(P##3); KEEPH(P##4); KEEPH(P##5); \
  KEEPH(P##6); KEEPH(P##7); KEEPH(P##8); KEEPH(P##9); KEEPH(P##10); KEEPH(P##11); \
  KEEPH(P##12); KEEPH(P##13); KEEPH(P##14); KEEPH(P##15);

// ih-weight init: layer==1 -> 16 h2 from ROWF; layer==0 -> 4 h2 from ROW0, rest 0
#define DECLIH(P, ROWF, ROW0) \
  h2 P##0, P##1, P##2, P##3, P##4, P##5, P##6, P##7, \
     P##8, P##9, P##10, P##11, P##12, P##13, P##14, P##15; \
  if (layer) { \
    const h2* _r = (const h2*)(ROWF); \
    half8 _a = LD8H(_r), _b = LD8H(_r + 4), _c = LD8H(_r + 8), _d = LD8H(_r + 12); \
    P##0 = H2OF(_a,0); P##1 = H2OF(_a,1); P##2  = H2OF(_a,2); P##3  = H2OF(_a,3); \
    P##4 = H2OF(_b,0); P##5 = H2OF(_b,1); P##6  = H2OF(_b,2); P##7  = H2OF(_b,3); \
    P##8 = H2OF(_c,0); P##9 = H2OF(_c,1); P##10 = H2OF(_c,2); P##11 = H2OF(_c,3); \
    P##12= H2OF(_d,0); P##13= H2OF(_d,1); P##14 = H2OF(_d,2); P##15 = H2OF(_d,3); \
  } else { \
    half8 _a = LD8H((const h2*)(ROW0)); \
    h2 _z = pkh(0.f, 0.f); \
    P##0 = H2OF(_a,0); P##1 = H2OF(_a,1); P##2 = H2OF(_a,2); P##3 = H2OF(_a,3); \
    P##4=_z; P##5=_z; P##6=_z; P##7=_z; P##8=_z; P##9=_z; P##10=_z; P##11=_z; \
    P##12=_z; P##13=_z; P##14=_z; P##15=_z; \
  }

#define EXTRACT16(P, A, B, C, D) \
  h2 P##0 = H2OF(A,0), P##1 = H2OF(A,1), P##2  = H2OF(A,2), P##3  = H2OF(A,3), \
     P##4 = H2OF(B,0), P##5 = H2OF(B,1), P##6  = H2OF(B,2), P##7  = H2OF(B,3), \
     P##8 = H2OF(C,0), P##9 = H2OF(C,1), P##10 = H2OF(C,2), P##11 = H2OF(C,3), \
     P##12= H2OF(D,0), P##13= H2OF(D,1), P##14 = H2OF(D,2), P##15 = H2OF(D,3);

// hh dots (own h)
#define DOT4V(j) { \
    aI = dot2(hv##j, wi##j, aI);                 \
    aF = dot2(hv##j, wf##j, aF);                 \
    aG = dot2(hv##j, wg##j, aG);                 \
    aO = dot2(hv##j, wo##j, aO); }
// ih dots (prev-layer h or x)
#define DOT4Y(j) { \
    aI = dot2(pv##j, yi##j, aI);                 \
    aF = dot2(pv##j, yf##j, aF);                 \
    aG = dot2(pv##j, yg##j, aG);                 \
    aO = dot2(pv##j, yo##j, aO); }

// ---------------------------------------------------------------------------
// fp32 -> fp16 convert (n multiple of 4)
// ---------------------------------------------------------------------------
__global__ __launch_bounds__(256) void cvt_f2h(
    const float* __restrict__ in, _Float16* __restrict__ out, int n)
{
    int base = (blockIdx.x * 256 + threadIdx.x) * 4;
    if (base < n) {
        float4 v = *(const float4*)(in + base);
        *(h2*)(out + base)     = pkh(v.x, v.y);
        *(h2*)(out + base + 2) = pkh(v.z, v.w);
    }
}

// ---------------------------------------------------------------------------
// MFMA GEMM: pre[M,512] = Ah[M,K] * Wh[512,K]^T + (b_ih + b_hh), fp16 output.
// ---------------------------------------------------------------------------
__global__ __launch_bounds__(256) void gemm_pre_mfma(
    const _Float16* __restrict__ A, int K, int rowStrideB, int t0, int tlog,
    const _Float16* __restrict__ W,
    const float* __restrict__ bi, const float* __restrict__ bh,
    _Float16* __restrict__ C)
{
    __shared__ h2 As2[64][20];
    __shared__ h2 Bs2[64][20];
    const int tid  = threadIdx.x;
    const int row0 = blockIdx.x * 64;
    const int col0 = blockIdx.y * 64;
    const int w    = tid >> 6;
    const int lane = tid & 63;
    const int qm   = (w >> 1) * 32;
    const int qn   = (w & 1) * 32;
    const int fm   = lane & 15;
    const int fq   = lane >> 4;
    const int tmask = (1 << tlog) - 1;
    const int lrow = tid >> 2;
    const int lk   = (tid & 3) * 8;

    f32x4 acc00 = {0,0,0,0}, acc01 = {0,0,0,0};
    f32x4 acc10 = {0,0,0,0}, acc11 = {0,0,0,0};

    for (int k0 = 0; k0 < K; k0 += 32) {
        {
            int rg = row0 + lrow;
            int b_idx = rg >> tlog, tt = rg & tmask;
            const _Float16* ap = A + (size_t)b_idx * rowStrideB +
                                 (size_t)(t0 + tt) * K + (k0 + lk);
            *(float4*)&As2[lrow][(tid & 3) * 4] = *(const float4*)ap;
            const _Float16* wp = W + (size_t)(col0 + lrow) * K + (k0 + lk);
            *(float4*)&Bs2[lrow][(tid & 3) * 4] = *(const float4*)wp;
        }
        __syncthreads();
        half8 a0 = *(const half8*)&As2[qm + fm][fq * 4];
        half8 a1 = *(const half8*)&As2[qm + 16 + fm][fq * 4];
        half8 b0 = *(const half8*)&Bs2[qn + fm][fq * 4];
        half8 b1 = *(const half8*)&Bs2[qn + 16 + fm][fq * 4];
        acc00 = __builtin_amdgcn_mfma_f32_16x16x32_f16(a0, b0, acc00, 0, 0, 0);
        acc01 = __builtin_amdgcn_mfma_f32_16x16x32_f16(a0, b1, acc01, 0, 0, 0);
        acc10 = __builtin_amdgcn_mfma_f32_16x16x32_f16(a1, b0, acc10, 0, 0, 0);
        acc11 = __builtin_amdgcn_mfma_f32_16x16x32_f16(a1, b1, acc11, 0, 0, 0);
        __syncthreads();
    }

    const int g0 = col0 + qn + fm;
    const int g1 = g0 + 16;
    const float bb0 = bi[g0] + bh[g0];
    const float bb1 = bi[g1] + bh[g1];
    const int m0 = row0 + qm + fq * 4;
    #pragma unroll
    for (int r = 0; r < 4; r++) {
        C[(size_t)(m0 + r) * Gn + g0]      = (_Float16)(acc00[r] + bb0);
        C[(size_t)(m0 + r) * Gn + g1]      = (_Float16)(acc01[r] + bb1);
        C[(size_t)(m0 + 16 + r) * Gn + g0] = (_Float16)(acc10[r] + bb0);
        C[(size_t)(m0 + 16 + r) * Gn + g1] = (_Float16)(acc11[r] + bb1);
    }
}

// ---------------------------------------------------------------------------
// scan01: layers 0 and 1 as a step-granular wavefront pipeline.
// grid (128, 2): blockIdx.y = layer. One block per (item, layer), 512 thr.
// Per thread (u = wv*16 + lane>>2, kq = lane&3): W_hh quarter-rows (64 h2) +
// W_ih quarter-rows (64 h2; layer0 uses 16, rest zeroed) pinned in regs.
// ih input: layer0 reads x rows; layer1 reads hs0 rows, gated on a per-item
// progress flag published by the layer-0 block every 8 steps (vmcnt drain +
// barrier + agent-scope release store; consumer uses agent-scope acquire).
// Deadlock-free: 256 blocks <= 256 CUs (1 block/CU at <=256 VGPR), deps
// acyclic (L1 <- L0 only), so even worst-case dispatch order completes.
// ---------------------------------------------------------------------------
__global__ __launch_bounds__(512)
__attribute__((amdgpu_waves_per_eu(2)))
void scan01(
    const _Float16* __restrict__ xh,     // [B, T, 32]
    const _Float16* __restrict__ w0h,    // [512, 32]  layer-0 W_ih (fp16)
    const _Float16* __restrict__ wrh,    // [2, 512, 128]; [0] = layer-1 W_ih
    const float* __restrict__ w_hh,      // [L, 512, 128]
    const float* __restrict__ b_ih, const float* __restrict__ b_hh, // [L,512]
    _Float16* __restrict__ hs0,          // [B, T, 128] layer-0 out
    _Float16* __restrict__ hs1,          // [B, T, 128] layer-1 out
    int* __restrict__ flags)             // [B] layer-0 progress
{
    const int b     = blockIdx.x;
    const int layer = blockIdx.y;          // 0 or 1
    const int tid   = threadIdx.x;
    const int lane  = tid & 63;
    const int wv    = tid >> 6;
    const int kq    = lane & 3;
    const int u     = wv * 16 + (lane >> 2);

    __shared__ h2 hbuf[2][Hn / 2];

    // recurrent weights (fp32 source -> packed h2 regs)
    const float* whl = w_hh + (size_t)layer * Gn * Hn;
    const float* rI = whl + (size_t)(0 * Hn + u) * Hn + kq * 32;
    const float* rF = whl + (size_t)(1 * Hn + u) * Hn + kq * 32;
    const float* rG = whl + (size_t)(2 * Hn + u) * Hn + kq * 32;
    const float* rO = whl + (size_t)(3 * Hn + u) * Hn + kq * 32;
    DECL16(wi, rI) DECL16(wf, rF) DECL16(wg, rG) DECL16(wo, rO)
    KEEP16(wi) KEEP16(wf) KEEP16(wg) KEEP16(wo)

    // input weights
    DECLIH(yi, wrh + (size_t)(0 * Hn + u) * Hn + kq * 32,
               w0h + (size_t)(0 * Hn + u) * Dn + kq * 8)
    DECLIH(yf, wrh + (size_t)(1 * Hn + u) * Hn + kq * 32,
               w0h + (size_t)(1 * Hn + u) * Dn + kq * 8)
    DECLIH(yg, wrh + (size_t)(2 * Hn + u) * Hn + kq * 32,
               w0h + (size_t)(2 * Hn + u) * Dn + kq * 8)
    DECLIH(yo, wrh + (size_t)(3 * Hn + u) * Hn + kq * 32,
               w0h + (size_t)(3 * Hn + u) * Dn + kq * 8)
    KEEP16(yi) KEEP16(yf) KEEP16(yg) KEEP16(yo)

    const float bI = b_ih[layer * Gn + 0 * Hn + u] + b_hh[layer * Gn + 0 * Hn + u];
    const float bF = b_ih[layer * Gn + 1 * Hn + u] + b_hh[layer * Gn + 1 * Hn + u];
    const float bG = b_ih[layer * Gn + 2 * Hn + u] + b_hh[layer * Gn + 2 * Hn + u];
    const float bO = b_ih[layer * Gn + 3 * Hn + u] + b_hh[layer * Gn + 3 * Hn + u];

    if (tid < Hn / 2) hbuf[0][tid] = pkh(0.f, 0.f);
    __syncthreads();

    _Float16* hswr = (layer ? hs1 : hs0) + (size_t)b * Tn * Hn + u;
    const _Float16* hsin = hs0 + (size_t)b * Tn * Hn;  // layer-1 input rows
    const _Float16* xrow = xh + (size_t)b * Tn * Dn;   // layer-0 input rows

    float cr = 0.f;
    int avail = 0;

    auto gate = [&](int need) {
        if (avail >= need) return;
        do {
            int a0 = 0;
            if (lane == 0)
                a0 = __hip_atomic_load(flags + b, __ATOMIC_ACQUIRE,
                                       __HIP_MEMORY_SCOPE_AGENT);
            avail = __builtin_amdgcn_readfirstlane(a0);
            if (avail < need) __builtin_amdgcn_s_sleep(16);
        } while (avail < need);
    };

    auto tick = [&](int t, half8 Pa, half8 Pb, half8 Pc, half8 Pd) {
        const h2* hrow = &hbuf[t & 1][kq * 16];
        half8 hA = LD8H(hrow);
        half8 hB = LD8H(hrow + 4);
        half8 hC = LD8H(hrow + 8);
        half8 hD = LD8H(hrow + 12);
        EXTRACT16(hv, hA, hB, hC, hD)
        EXTRACT16(pv, Pa, Pb, Pc, Pd)

        float aI = 0.f, aF = 0.f, aG = 0.f, aO = 0.f;
        DOT4V(0)  DOT4V(1)  DOT4V(2)  DOT4V(3)
        DOT4V(4)  DOT4V(5)  DOT4V(6)  DOT4V(7)
        DOT4V(8)  DOT4V(9)  DOT4V(10) DOT4V(11)
        DOT4V(12) DOT4V(13) DOT4V(14) DOT4V(15)
        DOT4Y(0)  DOT4Y(1)  DOT4Y(2)  DOT4Y(3)
        if (layer) {
            DOT4Y(4)  DOT4Y(5)  DOT4Y(6)  DOT4Y(7)
            DOT4Y(8)  DOT4Y(9)  DOT4Y(10) DOT4Y(11)
            DOT4Y(12) DOT4Y(13) DOT4Y(14) DOT4Y(15)
        }

        DPPADD(aI, 0xB1) DPPADD(aF, 0xB1) DPPADD(aG, 0xB1) DPPADD(aO, 0xB1)
        DPPADD(aI, 0x4E) DPPADD(aF, 0x4E) DPPADD(aG, 0x4E) DPPADD(aO, 0x4E)

        float iv = sigm(aI + bI);
        float fv = sigm(aF + bF);
        float gv = tanh_fast(aG + bG);
        float ov = sigm(aO + bO);
        cr = fv * cr + iv * gv;
        float hnew = ov * tanh_fast(cr);
        _Float16 hh = (_Float16)hnew;
        if (kq == 0) {
            ((_Float16*)hbuf[(t + 1) & 1])[u] = hh;
            *hswr = hh;
        }
        hswr += Hn;
        BAR_LDS();
    };

    // ---- prologue: rows 0 and 1 ----
    half8 pAa, pAb, pAc, pAd, pBa, pBb, pBc, pBd;
    {
        half8 z = {};
        pAb = pAc = pAd = z;
        pBb = pBc = pBd = z;
    }
    if (layer) {
        gate(2);
        const h2* r0 = (const h2*)(hsin + 0 * Hn + kq * 32);
        pAa = LD8H(r0); pAb = LD8H(r0 + 4); pAc = LD8H(r0 + 8); pAd = LD8H(r0 + 12);
        const h2* r1 = (const h2*)(hsin + 1 * Hn + kq * 32);
        pBa = LD8H(r1); pBb = LD8H(r1 + 4); pBc = LD8H(r1 + 8); pBd = LD8H(r1 + 12);
    } else {
        pAa = LD8H((const h2*)(xrow + 0 * Dn + kq * 8));
        pBa = LD8H((const h2*)(xrow + 1 * Dn + kq * 8));
    }

    for (int t = 0; t < Tn; t += 2) {
        tick(t, pAa, pAb, pAc, pAd);

        int r2 = (t + 2 < Tn) ? t + 2 : Tn - 1;
        int r3 = (t + 3 < Tn) ? t + 3 : Tn - 1;
        if (layer) {
            int need = (t + 4 < Tn) ? t + 4 : Tn;
            gate(need);
            const h2* r = (const h2*)(hsin + (size_t)r2 * Hn + kq * 32);
            pAa = LD8H(r); pAb = LD8H(r + 4); pAc = LD8H(r + 8); pAd = LD8H(r + 12);
        } else {
            pAa = LD8H((const h2*)(xrow + (size_t)r2 * Dn + kq * 8));
        }

        tick(t + 1, pBa, pBb, pBc, pBd);

        if (layer) {
            const h2* r = (const h2*)(hsin + (size_t)r3 * Hn + kq * 32);
            pBa = LD8H(r); pBb = LD8H(r + 4); pBc = LD8H(r + 8); pBd = LD8H(r + 12);
        } else {
            pBa = LD8H((const h2*)(xrow + (size_t)r3 * Dn + kq * 8));
            if (((t + 2) & 7) == 0) {
                asm volatile("s_waitcnt vmcnt(0)" ::: "memory");
                __syncthreads();
                if (tid == 0)
                    __hip_atomic_store(flags + b, t + 2, __ATOMIC_RELEASE,
                                       __HIP_MEMORY_SCOPE_AGENT);
            }
        }
    }
}

// ---------------------------------------------------------------------------
// LSTM scan v7 (layer 2): lane-adjacent k-split + DPP butterfly, fp16 pre.
// ---------------------------------------------------------------------------
__global__ __launch_bounds__(512)
__attribute__((amdgpu_waves_per_eu(2, 2)))
void lstm_scan(
    const _Float16* __restrict__ pre,  // [B*TCH, 512] fp16
    const float* __restrict__ w_hh,    // [512, 128] (this layer)
    _Float16* __restrict__ hs16,       // [B, T, H] layer output (fp16)
    float* __restrict__ h_state, float* __restrict__ c_state,
    int t0, int TCH, int first)
{
    const int b    = blockIdx.x;
    const int tid  = threadIdx.x;
    const int lane = tid & 63;
    const int wv   = tid >> 6;
    const int kq   = lane & 3;
    const int u    = wv * 16 + (lane >> 2);

    __shared__ h2 hbuf[2][Hn / 2];

    const float* rI = w_hh + (size_t)(0 * Hn + u) * Hn + kq * 32;
    const float* rF = w_hh + (size_t)(1 * Hn + u) * Hn + kq * 32;
    const float* rG = w_hh + (size_t)(2 * Hn + u) * Hn + kq * 32;
    const float* rO = w_hh + (size_t)(3 * Hn + u) * Hn + kq * 32;
    DECL16(wi, rI) DECL16(wf, rF) DECL16(wg, rG) DECL16(wo, rO)
    KEEP16(wi) KEEP16(wf) KEEP16(wg) KEEP16(wo)

    float cr = first ? 0.f : c_state[b * Hn + u];
    if (tid < Hn / 2) {
        h2 hv = pkh(0.f, 0.f);
        if (!first) hv = pkh(h_state[b * Hn + 2 * tid],
                             h_state[b * Hn + 2 * tid + 1]);
        hbuf[0][tid] = hv;
    }
    __syncthreads();

    const _Float16* pp = pre + (size_t)b * TCH * Gn + kq * Hn + u;
    _Float16* hswr = hs16 + ((size_t)b * Tn + t0) * Hn + u;

    const float mI = (kq == 0) ? 1.f : 0.f;
    const float mF = (kq == 1) ? 1.f : 0.f;
    const float mG = (kq == 2) ? 1.f : 0.f;
    const float mO = (kq == 3) ? 1.f : 0.f;

    float hlast = 0.f;

    auto body = [&](int t, float pv) {
        const h2* hrow = &hbuf[t & 1][kq * 16];
        half8 hAv = LD8H(hrow);
        half8 hBv = LD8H(hrow + 4);
        half8 hCv = LD8H(hrow + 8);
        half8 hDv = LD8H(hrow + 12);
        EXTRACT16(hv, hAv, hBv, hCv, hDv)

        float aI = 0.f, aF = 0.f, aG = 0.f, aO = 0.f;
        DOT4V(0)  DOT4V(1)  DOT4V(2)  DOT4V(3)
        DOT4V(4)  DOT4V(5)  DOT4V(6)  DOT4V(7)
        DOT4V(8)  DOT4V(9)  DOT4V(10) DOT4V(11)
        DOT4V(12) DOT4V(13) DOT4V(14) DOT4V(15)

        aI = fmaf(pv, mI, aI);
        aF = fmaf(pv, mF, aF);
        aG = fmaf(pv, mG, aG);
        aO = fmaf(pv, mO, aO);

        DPPADD(aI, 0xB1) DPPADD(aF, 0xB1) DPPADD(aG, 0xB1) DPPADD(aO, 0xB1)
        DPPADD(aI, 0x4E) DPPADD(aF, 0x4E) DPPADD(aG, 0x4E) DPPADD(aO, 0x4E)

        float iv = sigm(aI);
        float fv = sigm(aF);
        float gv = tanh_fast(aG);
        float ov = sigm(aO);
        cr = fv * cr + iv * gv;
        float hnew = ov * tanh_fast(cr);
        hlast = hnew;
        _Float16 hh = (_Float16)hnew;
        if (kq == 0) {
            ((_Float16*)hbuf[(t + 1) & 1])[u] = hh;
            *hswr = hh;
        }
        hswr += Hn;
        BAR_LDS();
    };

    float p0 = (float)pp[0];
    float p1 = (TCH > 1) ? (float)pp[Gn] : p0;
    const _Float16* pld = pp + 2 * (size_t)Gn;

    const int TCH2 = TCH - 2;
    for (int t = 0; t < TCH2; t++) {
        float pv = p0; p0 = p1;
        p1 = (float)*pld; pld += Gn;
        body(t, pv);
    }
    { float pv = p0; p0 = p1; body(TCH2, pv); }
    body(TCH2 + 1, p0);

    if (kq == 0) {
        h_state[b * Hn + u] = hlast;
        c_state[b * Hn + u] = cr;
    }
}

// ---------------------------------------------------------------------------
// Attention pooling + MLP head (reads fp16 hs). One block per batch item.
// ---------------------------------------------------------------------------
__global__ __launch_bounds__(256) void head_kernel(
    const _Float16* __restrict__ hs16,
    const float* __restrict__ w_attn, const float* __restrict__ b_attn,
    const float* __restrict__ w1, const float* __restrict__ b1,
    const float* __restrict__ w2, const float* __restrict__ b2,
    float* __restrict__ out)
{
    const int b = blockIdx.x;
    const int tid = threadIdx.x;
    __shared__ h2 wa2[Hn / 2];
    __shared__ __align__(16) float sc[Tn];
    __shared__ __align__(16) float red[256];
    __shared__ __align__(16) float ctx_sh[Hn];
    __shared__ __align__(16) float h1_sh[64];

    if (tid < Hn / 2) wa2[tid] = pkh(w_attn[2 * tid], w_attn[2 * tid + 1]);
    __syncthreads();

    const _Float16* hb = hs16 + (size_t)b * Tn * Hn;

    for (int t = tid; t < Tn; t += 256) {
        const h2* hp = (const h2*)(hb + (size_t)t * Hn);
        float s = 0.f;
        #pragma unroll
        for (int k = 0; k < 64; k++) s = dot2(hp[k], wa2[k], s);
        sc[t] = s + b_attn[0];
    }
    __syncthreads();

    float m = fmaxf(sc[tid], sc[tid + 256]);
    red[tid] = m; __syncthreads();
    for (int s_ = 128; s_ > 0; s_ >>= 1) {
        if (tid < s_) red[tid] = fmaxf(red[tid], red[tid + s_]);
        __syncthreads();
    }
    float mx = red[0];
    __syncthreads();
    float e0 = __expf(sc[tid] - mx), e1 = __expf(sc[tid + 256] - mx);
    sc[tid] = e0; sc[tid + 256] = e1;
    red[tid] = e0 + e1; __syncthreads();
    for (int s_ = 128; s_ > 0; s_ >>= 1) {
        if (tid < s_) red[tid] += red[tid + s_];
        __syncthreads();
    }
    float inv = 1.f / red[0];
    __syncthreads();

    {
        int jj = tid & 127, half = tid >> 7;
        float a = 0.f;
        for (int t = half * 256; t < half * 256 + 256; t++)
            a += sc[t] * (float)hb[(size_t)t * Hn + jj];
        red[tid] = a;
        __syncthreads();
        if (tid < Hn) ctx_sh[tid] = (red[tid] + red[tid + Hn]) * inv;
        __syncthreads();
    }

    if (tid < 64) {
        const float4* wvv = (const float4*)(w1 + (size_t)tid * Hn);
        const float4* cv = (const float4*)ctx_sh;
        float s = 0.f;
        #pragma unroll
        for (int k = 0; k < 32; k++) {
            float4 a = wvv[k], c = cv[k];
            s += a.x * c.x + a.y * c.y + a.z * c.z + a.w * c.w;
        }
        h1_sh[tid] = fmaxf(s + b1[tid], 0.f);
    }
    __syncthreads();

    if (tid < 4) {
        float s = 0.f;
        const float* wvv = w2 + tid * 64;
        #pragma unroll
        for (int k = 0; k < 64; k++) s += wvv[k] * h1_sh[k];
        out[b * 4 + tid] = s + b2[tid];
    }
}

// ---------------------------------------------------------------------------
extern "C" void kernel_launch(void* const* d_in, const int* in_sizes, int n_in,
                              void* d_out, int out_size, void* d_ws, size_t ws_size,
                              hipStream_t stream)
{
    const float* x        = (const float*)d_in[0];
    const float* w_ih0    = (const float*)d_in[1];
    const float* w_ih_rest= (const float*)d_in[2];
    const float* w_hh     = (const float*)d_in[3];
    const float* b_ih     = (const float*)d_in[4];
    const float* b_hh     = (const float*)d_in[5];
    const float* w_attn   = (const float*)d_in[6];
    const float* b_attn   = (const float*)d_in[7];
    const float* w1       = (const float*)d_in[8];
    const float* b1       = (const float*)d_in[9];
    const float* w2       = (const float*)d_in[10];
    const float* b2       = (const float*)d_in[11];
    float* out = (float*)d_out;

    const size_t nX  = (size_t)Bn * Tn * Dn;       // 2,097,152
    const size_t nHS = (size_t)Bn * Tn * Hn;       // 8,388,608
    const size_t nW0 = (size_t)Gn * Dn;            // 16,384
    const size_t nWR = (size_t)(Ln - 1) * Gn * Hn; // 131,072
    const size_t nPRE = (size_t)Bn * Tn * Gn;      // 33,554,432 (fp16)

    float* ws    = (float*)d_ws;
    float* h_st  = ws;                       // 16384 floats
    float* c_st  = h_st + (size_t)Bn * Hn;   // 16384 floats
    int*   flags = (int*)(c_st + (size_t)Bn * Hn);  // 128 ints, pad to 256 floats
    _Float16* preh = (_Float16*)((float*)flags + 256);
    _Float16* xh   = preh + nPRE;
    _Float16* hs0  = xh + nX;
    _Float16* hs1  = hs0 + nHS;
    _Float16* hs2  = hs1 + nHS;
    _Float16* w0h  = hs2 + nHS;
    _Float16* wrh  = w0h + nW0;
    // total: ~122 MB (< the >=155 MB this workspace has held in prior rounds)

    hipMemsetAsync(flags, 0, Bn * sizeof(int), stream);

    cvt_f2h<<<(int)((nX / 4 + 255) / 256), 256, 0, stream>>>(x, xh, (int)nX);
    cvt_f2h<<<(int)((nW0 / 4 + 255) / 256), 256, 0, stream>>>(w_ih0, w0h, (int)nW0);
    cvt_f2h<<<(int)((nWR / 4 + 255) / 256), 256, 0, stream>>>(w_ih_rest, wrh, (int)nWR);

    // layers 0 + 1: fused wavefront pipeline (256 blocks, all co-resident)
    scan01<<<dim3(Bn, 2), 512, 0, stream>>>(xh, w0h, wrh, w_hh, b_ih, b_hh,
                                            hs0, hs1, flags);

    // layer 2: MFMA pre-GEMM (fp16 out) + scan
    gemm_pre_mfma<<<dim3(Bn * Tn / 64, 8), 256, 0, stream>>>(
        hs1, Hn, Tn * Hn, 0, 9,
        wrh + (size_t)Gn * Hn, b_ih + 2 * Gn, b_hh + 2 * Gn, preh);
    lstm_scan<<<Bn, 512, 0, stream>>>(preh, w_hh + 2 * (size_t)Gn * Hn,
                                      hs2, h_st, c_st, 0, Tn, 1);

    head_kernel<<<Bn, 256, 0, stream>>>(hs2, w_attn, b_attn, w1, b1, w2, b2, out);
}